// Round 1
// baseline (92.325 us; speedup 1.0000x reference)
//
#include <hip/hip_runtime.h>

// MultiTierLoss: B=4096 rows, D=1000 cols, fp32.
// loss_row = sum_{t0 pairs} relu(1 - s_i + s_j)/26250
//          + sum_{t1 pairs} relu(1 - s_i + s_j)/2500
//          + 2/1000 * sum_{k<n, j>=n} relu(1 - s_k + s_j)
// out = mean over rows.

#define BQ 4096
#define DQ 1000

__global__ __launch_bounds__(256) void mtl_row_kernel(const float* __restrict__ scores,
                                                      const int* __restrict__ labels,
                                                      float* __restrict__ row_loss) {
    const int row = blockIdx.x;
    __shared__ float s[DQ];
    __shared__ int n_sh;
    __shared__ float wsum[4];

    const float* sr = scores + (size_t)row * DQ;
    for (int j = threadIdx.x; j < DQ; j += 256) s[j] = sr[j];

    if (threadIdx.x == 0) {
        // n <= MAX_REL = 8 by construction; labels[row,k] = k if k < n else -1
        const int* lr = labels + (size_t)row * DQ;
        int n = 0;
        #pragma unroll
        for (int k = 0; k < 8; ++k) n += (lr[k] > -1) ? 1 : 0;
        n_sh = n;
    }
    __syncthreads();
    const int n = n_sh;

    float acc = 0.0f;
    for (int j = threadIdx.x; j < DQ; j += 256) {
        const float sj = s[j];
        // tier 0: relatives cols [0,50), negatives cols [475,1000)
        if (j >= 475) {
            float t = 0.0f;
            #pragma unroll 10
            for (int i = 0; i < 50; ++i) t += fmaxf(1.0f - s[i] + sj, 0.0f);
            acc += t * (1.0f / 26250.0f);   // /(50*525)
        }
        // tier 1: relatives cols [475,525), negatives cols [950,1000)
        if (j >= 950) {
            float t = 0.0f;
            #pragma unroll 10
            for (int i = 475; i < 525; ++i) t += fmaxf(1.0f - s[i] + sj, 0.0f);
            acc += t * (1.0f / 2500.0f);    // /(50*50)
        }
        // gt: relatives cols [0,n), negatives cols [n,1000)
        if (j >= n) {
            float t = 0.0f;
            for (int k = 0; k < n; ++k) t += fmaxf(1.0f - s[k] + sj, 0.0f);
            acc += t * (2.0f / 1000.0f);    // GT_FACTOR / D
        }
    }

    // block reduction: wave64 shuffle then LDS across the 4 waves
    #pragma unroll
    for (int off = 32; off > 0; off >>= 1) acc += __shfl_down(acc, off, 64);
    const int lane = threadIdx.x & 63;
    const int wid  = threadIdx.x >> 6;
    if (lane == 0) wsum[wid] = acc;
    __syncthreads();
    if (threadIdx.x == 0) row_loss[row] = wsum[0] + wsum[1] + wsum[2] + wsum[3];
}

__global__ __launch_bounds__(256) void mtl_reduce_kernel(const float* __restrict__ row_loss,
                                                         float* __restrict__ out) {
    __shared__ float wsum[4];
    float acc = 0.0f;
    for (int i = threadIdx.x; i < BQ; i += 256) acc += row_loss[i];
    #pragma unroll
    for (int off = 32; off > 0; off >>= 1) acc += __shfl_down(acc, off, 64);
    const int lane = threadIdx.x & 63;
    const int wid  = threadIdx.x >> 6;
    if (lane == 0) wsum[wid] = acc;
    __syncthreads();
    if (threadIdx.x == 0) out[0] = (wsum[0] + wsum[1] + wsum[2] + wsum[3]) * (1.0f / (float)BQ);
}

extern "C" void kernel_launch(void* const* d_in, const int* in_sizes, int n_in,
                              void* d_out, int out_size, void* d_ws, size_t ws_size,
                              hipStream_t stream) {
    const float* scores = (const float*)d_in[0];
    const int*   labels = (const int*)d_in[1];
    float* row_loss = (float*)d_ws;      // BQ floats = 16 KB scratch
    float* out = (float*)d_out;

    mtl_row_kernel<<<BQ, 256, 0, stream>>>(scores, labels, row_loss);
    mtl_reduce_kernel<<<1, 256, 0, stream>>>(row_loss, out);
}

// Round 2
// 88.387 us; speedup vs baseline: 1.0446x; 1.0446x over previous
//
#include <hip/hip_runtime.h>
#include <float.h>

// MultiTierLoss: B=4096 rows, D=1000 cols, fp32.
// Tier0: rel [0,50) vs neg [475,1000), /26250
// Tier1: rel [475,525) vs neg [950,1000), /2500
// GT:    rel [0,n) vs neg [n,1000), *2/1000, n<=8
// Algorithmic speedup: sum_i relu(x - r_i) over sorted r = c*x - prefix[c],
// c = #{r_i < x} via 6-step branchless binary search (pad to 64 w/ FLT_MAX).

#define BQ 4096
#define DQ 1000

__global__ __launch_bounds__(256) void mtl_row_kernel(const float* __restrict__ scores,
                                                      const int* __restrict__ labels,
                                                      float* __restrict__ row_loss) {
    const int row  = blockIdx.x;
    const int tid  = threadIdx.x;
    const int lane = tid & 63;
    const int wid  = tid >> 6;

    __shared__ float s[DQ];
    __shared__ float sorted0[64];   // tier0 relatives, sorted asc, FLT_MAX pad
    __shared__ float pre0[65];      // exclusive prefix sums of sorted0
    __shared__ int   n_sh;
    __shared__ float wsum[4];

    // stage row (row*4000 bytes is 16B-aligned -> float4 ok)
    const float* sr = scores + (size_t)row * DQ;
    if (tid < 250) {
        float4 v = ((const float4*)sr)[tid];
        s[tid * 4 + 0] = v.x; s[tid * 4 + 1] = v.y;
        s[tid * 4 + 2] = v.z; s[tid * 4 + 3] = v.w;
    }
    if (tid == 0) {
        const int* lr = labels + (size_t)row * DQ;
        int n = 0;
        #pragma unroll
        for (int k = 0; k < 8; ++k) n += (lr[k] > -1) ? 1 : 0;
        n_sh = n;
    }
    __syncthreads();
    const int n = n_sh;   // wave-uniform

    float acc = 0.0f;

    // ---------- phase 1: wave0 sorts tier0 relatives; waves 1-3 do tier1 + GT
    if (wid == 0) {
        if (lane >= 50) sorted0[lane] = FLT_MAX;
        else {
            float v = s[lane];
            int rank = 0;
            for (int k = 0; k < 50; ++k) {
                float sk = s[k];                       // LDS broadcast
                rank += (sk < v || (sk == v && k < lane)) ? 1 : 0;
            }
            sorted0[rank] = v;
        }
    } else {
        // tier1: lanes hold one negative j each (j = 950+lane, lane<50),
        // iterate relatives i = 475..524 split across waves 1..3
        float sj = s[950 + (lane < 50 ? lane : 0)];
        float t1 = 0.0f;
        for (int i = wid - 1; i < 50; i += 3) {
            float ri = s[475 + i];                     // LDS broadcast
            t1 += fmaxf(1.0f - ri + sj, 0.0f);
        }
        if (lane < 50) acc += t1 * (1.0f / 2500.0f);

        // GT: negatives j distributed over threads 64..255 (192 threads);
        // inner trip n is wave-uniform (same row) -> no divergence
        float tgt = 0.0f;
        for (int j = tid - 64; j < DQ; j += 192) {
            if (j >= n) {
                float x = 1.0f + s[j];
                float t = 0.0f;
                for (int k = 0; k < n; ++k)
                    t += fmaxf(x - s[k], 0.0f);        // s[k] broadcast
                tgt += t;
            }
        }
        acc += tgt * (2.0f / 1000.0f);
    }
    __syncthreads();

    // ---------- phase 1b: wave0 exclusive-scans sorted0 -> pre0
    if (wid == 0) {
        float val = (lane < 50) ? sorted0[lane] : 0.0f;
        #pragma unroll
        for (int off = 1; off < 64; off <<= 1) {
            float tmp = __shfl_up(val, off, 64);
            if (lane >= off) val += tmp;
        }
        pre0[lane + 1] = val;
        if (lane == 0) pre0[0] = 0.0f;
    }
    __syncthreads();

    // ---------- phase 2: tier0 via binary search, all threads
    float t0 = 0.0f;
    for (int j = 475 + tid; j < DQ; j += 256) {
        float x = 1.0f + s[j];
        int c = 0;
        #pragma unroll
        for (int st = 32; st >= 1; st >>= 1)          // count of sorted0[k] < x
            c += (sorted0[c + st - 1] < x) ? st : 0;  // pad=FLT_MAX => c<=50
        t0 += (float)c * x - pre0[c];
    }
    acc += t0 * (1.0f / 26250.0f);

    // ---------- block reduction
    #pragma unroll
    for (int off = 32; off > 0; off >>= 1) acc += __shfl_down(acc, off, 64);
    if (lane == 0) wsum[wid] = acc;
    __syncthreads();
    if (tid == 0) row_loss[row] = wsum[0] + wsum[1] + wsum[2] + wsum[3];
}

__global__ __launch_bounds__(256) void mtl_reduce_kernel(const float* __restrict__ row_loss,
                                                         float* __restrict__ out) {
    __shared__ float wsum[4];
    float acc = 0.0f;
    for (int i = threadIdx.x; i < BQ; i += 256) acc += row_loss[i];
    #pragma unroll
    for (int off = 32; off > 0; off >>= 1) acc += __shfl_down(acc, off, 64);
    const int lane = threadIdx.x & 63;
    const int wid  = threadIdx.x >> 6;
    if (lane == 0) wsum[wid] = acc;
    __syncthreads();
    if (threadIdx.x == 0) out[0] = (wsum[0] + wsum[1] + wsum[2] + wsum[3]) * (1.0f / (float)BQ);
}

extern "C" void kernel_launch(void* const* d_in, const int* in_sizes, int n_in,
                              void* d_out, int out_size, void* d_ws, size_t ws_size,
                              hipStream_t stream) {
    const float* scores = (const float*)d_in[0];
    const int*   labels = (const int*)d_in[1];
    float* row_loss = (float*)d_ws;      // 16 KB scratch
    float* out = (float*)d_out;

    mtl_row_kernel<<<BQ, 256, 0, stream>>>(scores, labels, row_loss);
    mtl_reduce_kernel<<<1, 256, 0, stream>>>(row_loss, out);
}